// Round 1
// baseline (1040.878 us; speedup 1.0000x reference)
//
#include <hip/hip_runtime.h>
#include <hip/hip_bf16.h>

// ---------------------------------------------------------------------------
// GumbelNeRF fused kernel (round 1: fp32 VALU, correctness-first)
//
// N=131072 pts, E=8 experts, W=128, H=64, DX=63, DV=27.
// Per block: 64 points, 256 threads. Phases:
//   0: PE(xyz)->sPE (fp32), PE(viewdir)->sVD (bf16), stage w_sig
//   A: y = relu(pe @ W_enc + b_enc) -> sY (fp32, LDS)
//   B: for e in 0..7: S_e = relu(y @ W_sh[e] + b_sh[e]) in regs (8x4 tile),
//      sigma_e = softplus(S_e . w_sig + b_sig); score = log(sigma+1e-10)/TEMP
//      + gumbel(threefry);  running argmax; winning S row -> sSbest (bf16).
//   C: bucket points by winning expert; h = relu([S*,vd] @ W_r1[e] + b_r1),
//      rgb = sigmoid(h @ W_r2[e] + b_r2); write rgb + pooled sigma.
//
// Gumbel RNG: JAX threefry2x32, key(42) -> (k0,k1)=(0,42), PARTITIONABLE
// path (JAX >= 0.4.36 default): counter = (hi=0, lo=flat_idx), bits = o0^o1,
// u = bitcast(bits>>9 | 0x3f800000) - 1.0f, g = -log(-log(u+1e-20)+1e-20).
// FALLBACK (legacy jax_threefry_partitionable=False), if absmax fails with
// sparse large errors: half=524288; i<half: bits=o0 of block (i, i+half);
// else bits=o1 of block (i-half, i).
// ---------------------------------------------------------------------------

#define NPTS 131072
#define PT 64
#define NTH 256
#define NBLK (NPTS / PT)

// LDS byte offsets (total 63008 <= 64KB)
#define OFF_Y     0        // 64*128*4 = 32768 ; phase C: sH[64][65] f32 (16640)
#define OFF_W     32768    // staging 16*128*4 = 8192 ; sRed 64*33*4 = 8448
#define OFF_U     41216    // sPE 64*64*4 = 16384 | sSbest 64*128*2 = 16384
#define OFF_VD    57600    // 64*28*2 = 3584 (bf16, stride 28)
#define OFF_WSIG  61184    // 128*4
#define OFF_BSC   61696    // best score 64*4
#define OFF_BSG   61952    // best sigma 64*4
#define OFF_BID   62208    // best idx   64*4
#define OFF_IMP   62464    // improved   64*4
#define OFF_LIST  62720    // 64*4
#define OFF_CNT   62976    // 4
#define SMEM_SZ   63008

__device__ __forceinline__ unsigned rotl32(unsigned x, int d) {
  return (x << d) | (x >> (32 - d));
}

// JAX threefry2x32, 20 rounds, keys (0, 42), counter (0, flat). Returns gumbel.
__device__ __forceinline__ float gumbel_for(unsigned flat) {
  const unsigned k0 = 0u, k1 = 42u;
  const unsigned ks2 = k0 ^ k1 ^ 0x1BD11BDAu;
  unsigned x0 = 0u + k0;
  unsigned x1 = flat + k1;
#define TF_RND(r) { x0 += x1; x1 = rotl32(x1, r); x1 ^= x0; }
  TF_RND(13) TF_RND(15) TF_RND(26) TF_RND(6)
  x0 += k1;  x1 += ks2 + 1u;
  TF_RND(17) TF_RND(29) TF_RND(16) TF_RND(24)
  x0 += ks2; x1 += k0 + 2u;
  TF_RND(13) TF_RND(15) TF_RND(26) TF_RND(6)
  x0 += k0;  x1 += k1 + 3u;
  TF_RND(17) TF_RND(29) TF_RND(16) TF_RND(24)
  x0 += k1;  x1 += ks2 + 4u;
  TF_RND(13) TF_RND(15) TF_RND(26) TF_RND(6)
  x0 += ks2; x1 += k0 + 5u;
#undef TF_RND
  unsigned bits = x0 ^ x1;  // partitionable 32-bit fold
  float u = __uint_as_float((bits >> 9) | 0x3f800000u) - 1.0f;
  return -logf(-logf(u + 1e-20f) + 1e-20f);
}

__device__ __forceinline__ void fma4(float4& a, float s, float4 b) {
  a.x = fmaf(s, b.x, a.x);
  a.y = fmaf(s, b.y, a.y);
  a.z = fmaf(s, b.z, a.z);
  a.w = fmaf(s, b.w, a.w);
}

__global__ __launch_bounds__(NTH, 2)
void nerf_moe_kernel(const float* __restrict__ x,
                     const float* __restrict__ W_enc, const float* __restrict__ b_enc,
                     const float* __restrict__ W_sh,  const float* __restrict__ b_sh,
                     const float* __restrict__ w_sig, const float* __restrict__ b_sig,
                     const float* __restrict__ W_r1,  const float* __restrict__ b_r1,
                     const float* __restrict__ W_r2,  const float* __restrict__ b_r2,
                     float* __restrict__ out) {
  __shared__ __align__(16) unsigned char smem[SMEM_SZ];
  float*  sY     = (float*)(smem + OFF_Y);
  float*  sW     = (float*)(smem + OFF_W);
  float*  sRed   = (float*)(smem + OFF_W);          // stride 33 (bank-pad)
  float*  sPE    = (float*)(smem + OFF_U);          // [64][64] fp32 (phase 0/A)
  __hip_bfloat16* sSbest = (__hip_bfloat16*)(smem + OFF_U); // [64][128] (B/C)
  __hip_bfloat16* sVD    = (__hip_bfloat16*)(smem + OFF_VD); // [64][28]
  float*  sWsig  = (float*)(smem + OFF_WSIG);
  float*  sBsc   = (float*)(smem + OFF_BSC);
  float*  sBsg   = (float*)(smem + OFF_BSG);
  int*    sBid   = (int*)(smem + OFF_BID);
  int*    sImp   = (int*)(smem + OFF_IMP);
  int*    sList  = (int*)(smem + OFF_LIST);
  int*    sCnt   = (int*)(smem + OFF_CNT);
  float*  sH     = (float*)(smem + OFF_Y);          // [64][65] (phase C)

  const int t  = threadIdx.x;
  const int n0 = blockIdx.x * PT;
  const int jg = t & 31;       // 32 j-groups of 4
  const int pg = t >> 5;       // 8 p-groups of 8
  const int j4 = jg * 4;
  const int p8 = pg * 8;

  // ---- phase 0: positional encodings ----
  for (int idx = t; idx < PT * 64; idx += NTH) {
    int p = idx >> 6, f = idx & 63;
    const float* xr = x + (size_t)(n0 + p) * 6;
    float v;
    if (f < 3)       v = xr[f];
    else if (f < 33) { int q = f - 3;  v = sinf(xr[q % 3] * (float)(1 << (q / 3))); }
    else if (f < 63) { int q = f - 33; v = cosf(xr[q % 3] * (float)(1 << (q / 3))); }
    else             v = 0.0f;   // zero-pad K=63 -> 64
    sPE[p * 64 + f] = v;
  }
  for (int idx = t; idx < PT * 27; idx += NTH) {
    int p = idx / 27, f = idx - p * 27;
    const float* xr = x + (size_t)(n0 + p) * 6 + 3;
    float v;
    if (f < 3)       v = xr[f];
    else if (f < 15) { int q = f - 3;  v = sinf(xr[q % 3] * (float)(1 << (q / 3))); }
    else             { int q = f - 15; v = cosf(xr[q % 3] * (float)(1 << (q / 3))); }
    sVD[p * 28 + f] = __float2bfloat16(v);
  }
  if (t < 128) sWsig[t] = w_sig[t];
  __syncthreads();

  float4 acc[8];

  // ---- phase A: y = relu(pe @ W_enc + b_enc) ----
  #pragma unroll
  for (int i = 0; i < 8; ++i) acc[i] = make_float4(0.f, 0.f, 0.f, 0.f);
  for (int kc = 0; kc < 4; ++kc) {
    __syncthreads();
    for (int s = t; s < 512; s += NTH) {       // 16 rows x 128 cols
      int f = s * 4;
      int r = kc * 16 + (f >> 7);
      int j = f & 127;
      float4 v = (r < 63) ? *(const float4*)(W_enc + r * 128 + j)
                          : make_float4(0.f, 0.f, 0.f, 0.f);
      ((float4*)sW)[s] = v;
    }
    __syncthreads();
    #pragma unroll
    for (int q = 0; q < 4; ++q) {
      float4 wv[4];
      #pragma unroll
      for (int kk = 0; kk < 4; ++kk)
        wv[kk] = *(const float4*)(sW + (q * 4 + kk) * 128 + j4);
      #pragma unroll
      for (int i = 0; i < 8; ++i) {
        float4 yv = *(const float4*)(sPE + (p8 + i) * 64 + kc * 16 + q * 4);
        fma4(acc[i], yv.x, wv[0]); fma4(acc[i], yv.y, wv[1]);
        fma4(acc[i], yv.z, wv[2]); fma4(acc[i], yv.w, wv[3]);
      }
    }
  }
  {
    float4 bb = *(const float4*)(b_enc + j4);
    #pragma unroll
    for (int i = 0; i < 8; ++i) {
      float4 v;
      v.x = fmaxf(acc[i].x + bb.x, 0.f); v.y = fmaxf(acc[i].y + bb.y, 0.f);
      v.z = fmaxf(acc[i].z + bb.z, 0.f); v.w = fmaxf(acc[i].w + bb.w, 0.f);
      *(float4*)(sY + (p8 + i) * 128 + j4) = v;
    }
  }

  // ---- phase B: expert loop, running gumbel-argmax ----
  for (int e = 0; e < 8; ++e) {
    #pragma unroll
    for (int i = 0; i < 8; ++i) acc[i] = make_float4(0.f, 0.f, 0.f, 0.f);
    const float* We = W_sh + e * (128 * 128);
    for (int kc = 0; kc < 8; ++kc) {
      __syncthreads();
      {
        const float4* src = (const float4*)(We + kc * 2048);
        ((float4*)sW)[t]       = src[t];
        ((float4*)sW)[t + 256] = src[t + 256];
      }
      __syncthreads();
      #pragma unroll
      for (int q = 0; q < 4; ++q) {
        float4 wv[4];
        #pragma unroll
        for (int kk = 0; kk < 4; ++kk)
          wv[kk] = *(const float4*)(sW + (q * 4 + kk) * 128 + j4);
        #pragma unroll
        for (int i = 0; i < 8; ++i) {
          float4 yv = *(const float4*)(sY + (p8 + i) * 128 + kc * 16 + q * 4);
          fma4(acc[i], yv.x, wv[0]); fma4(acc[i], yv.y, wv[1]);
          fma4(acc[i], yv.z, wv[2]); fma4(acc[i], yv.w, wv[3]);
        }
      }
    }
    // bias + relu (keep in regs for sigma dot and S-copy)
    {
      float4 bb = *(const float4*)(b_sh + e * 128 + j4);
      #pragma unroll
      for (int i = 0; i < 8; ++i) {
        acc[i].x = fmaxf(acc[i].x + bb.x, 0.f);
        acc[i].y = fmaxf(acc[i].y + bb.y, 0.f);
        acc[i].z = fmaxf(acc[i].z + bb.z, 0.f);
        acc[i].w = fmaxf(acc[i].w + bb.w, 0.f);
      }
    }
    __syncthreads();   // all sW reads done; reuse as sRed
    {
      float4 ws = *(const float4*)(sWsig + j4);
      #pragma unroll
      for (int i = 0; i < 8; ++i) {
        float part = acc[i].x * ws.x + acc[i].y * ws.y +
                     acc[i].z * ws.z + acc[i].w * ws.w;
        sRed[(p8 + i) * 33 + jg] = part;
      }
    }
    __syncthreads();
    if (t < PT) {
      float s = 0.f;
      #pragma unroll
      for (int j = 0; j < 32; ++j) s += sRed[t * 33 + j];
      float dotv = s + b_sig[0];
      float sig  = fmaxf(dotv, 0.f) + log1pf(expf(-fabsf(dotv)));  // softplus
      float z    = logf(sig + 1e-10f) / 0.166667f;
      float score = z + gumbel_for((unsigned)((n0 + t) * 8 + e));
      bool imp = (e == 0) || (score > sBsc[t]);   // strict >: first-max ties
      sImp[t] = imp ? 1 : 0;
      if (imp) { sBsc[t] = score; sBsg[t] = sig; sBid[t] = e; }
    }
    __syncthreads();
    #pragma unroll
    for (int i = 0; i < 8; ++i) {
      if (sImp[p8 + i]) {
        __hip_bfloat16* d = sSbest + (p8 + i) * 128 + j4;
        d[0] = __float2bfloat16(acc[i].x);
        d[1] = __float2bfloat16(acc[i].y);
        d[2] = __float2bfloat16(acc[i].z);
        d[3] = __float2bfloat16(acc[i].w);
      }
    }
  }
  __syncthreads();

  // ---- phase C: rgb for winning expert, bucketed ----
  for (int e = 0; e < 8; ++e) {
    if (t == 0) {
      int c = 0;
      for (int p = 0; p < PT; ++p) if (sBid[p] == e) sList[c++] = p;
      *sCnt = c;
    }
    __syncthreads();
    int cnt = *sCnt;
    if (cnt > 0) {
      int hj = t & 63;
      for (int m = t >> 6; m < cnt; m += 4) {
        int p = sList[m];
        float a = b_r1[e * 64 + hj];
        const float* w1 = W_r1 + e * (155 * 64) + hj;
        const __hip_bfloat16* sb = sSbest + p * 128;
        #pragma unroll 4
        for (int c = 0; c < 128; ++c)
          a = fmaf(__bfloat162float(sb[c]), w1[c * 64], a);
        const __hip_bfloat16* vdp = sVD + p * 28;
        #pragma unroll
        for (int c = 0; c < 27; ++c)
          a = fmaf(__bfloat162float(vdp[c]), w1[(128 + c) * 64], a);
        sH[m * 65 + hj] = fmaxf(a, 0.f);
      }
    }
    __syncthreads();
    if (t < cnt * 3) {
      int m = t / 3, o = t - m * 3;
      float a = b_r2[e * 3 + o];
      const float* w2 = W_r2 + e * 192 + o;
      #pragma unroll 8
      for (int j = 0; j < 64; ++j)
        a = fmaf(sH[m * 65 + j], w2[j * 3], a);
      float rgbv = 1.0f / (1.0f + expf(-a));
      out[(size_t)(n0 + sList[m]) * 4 + o] = rgbv;
    }
    __syncthreads();
  }
  if (t < PT) out[(size_t)(n0 + t) * 4 + 3] = sBsg[t];
}

extern "C" void kernel_launch(void* const* d_in, const int* in_sizes, int n_in,
                              void* d_out, int out_size, void* d_ws, size_t ws_size,
                              hipStream_t stream) {
  (void)in_sizes; (void)n_in; (void)d_ws; (void)ws_size; (void)out_size;
  const float* x     = (const float*)d_in[0];
  const float* W_enc = (const float*)d_in[1];
  const float* b_enc = (const float*)d_in[2];
  const float* W_sh  = (const float*)d_in[3];
  const float* b_sh  = (const float*)d_in[4];
  const float* w_sig = (const float*)d_in[5];
  const float* b_sig = (const float*)d_in[6];
  const float* W_r1  = (const float*)d_in[7];
  const float* b_r1  = (const float*)d_in[8];
  const float* W_r2  = (const float*)d_in[9];
  const float* b_r2  = (const float*)d_in[10];
  float* outp = (float*)d_out;
  nerf_moe_kernel<<<NBLK, NTH, 0, stream>>>(x, W_enc, b_enc, W_sh, b_sh,
                                            w_sig, b_sig, W_r1, b_r1,
                                            W_r2, b_r2, outp);
}

// Round 2
// 322.065 us; speedup vs baseline: 3.2319x; 3.2319x over previous
//
#include <hip/hip_runtime.h>
#include <hip/hip_bf16.h>

// ---------------------------------------------------------------------------
// GumbelNeRF fused kernel, round 2: fp16-split MFMA.
//
// prep_kernel: splits W_enc/W_sh (fp32) into scaled fp16 pairs (v ~= hi +
// lo/2048) and W_r1 into fp16, laid out FRAGMENT-LINEAR in d_ws: for tile
// (nt,kt[,e]) lane L reads elements [tile*512 + L*8, +8) as one 16B load.
// ws layout (fp16 elems): encH@0(8192) encL@8192 shH@16384(131072)
// shL@147456 r1H@278528(81920) -> 720896 B total.
//
// main kernel (64 pts/block, 4 waves):
//   0: PE -> sPEh/sPEl (f16 split), viewdir PE -> sVD (f16)
//   A: Y = relu(PE @ W_enc + b) via MFMA (3-product split), Y hi/lo -> LDS
//   hoist: Y A-frags (Ah/Al, 32 frags = 128 VGPR); vd -> sSB cols 128..159
//   B: per expert e: S-tile in regs (nt-split: wave w owns j-cols
//      [32w,32w+32)); sigma dot via LDS reduction; t<64: softplus ->
//      score=log(sig+1e-10)/TEMP + threefry-gumbel -> running argmax ->
//      __ballot mask; winners' S rows -> sSB (f16).
//   C: bucket pts by winner; h = relu([S;vd] @ W_r1[e]) via MFMA (f16,
//      1 product); rgb = sigmoid(h @ W_r2 + b) from LDS-staged W_r2.
// Gumbel RNG identical to round 1 (verified passing).
// ---------------------------------------------------------------------------

#define NPTS 131072
#define PT 64
#define NTH 256
#define NBLK (NPTS / PT)
#define INV2048 (1.0f / 2048.0f)

// ws sections (f16 element offsets)
#define WS_ENC_H 0
#define WS_ENC_L 8192
#define WS_SH_H  16384
#define WS_SH_L  147456
#define WS_R1_H  278528

// LDS offsets (bytes), total 62768
#define OFF_Y    0      // sYh [64][136] f16 (17408); alias sRed [64][68] f32, sH [64][68] f32
#define OFF_YL   17408  // sYl (17408); alias sW2 (6144) + sB2 (96)
#define OFF_SB   34816  // sSB [64][168] f16 (21504); alias sPEh(9216)@+0, sPEl(9216)@+9216
#define OFF_VD   56320  // [64][28] f16 (3584)
#define OFF_SC   59904  // best score f32[64]
#define OFF_SG   60160  // best sigma f32[64]
#define OFF_BID  60416  // best idx  i32[64]
#define OFF_MASK 60672  // u64 winner mask
#define OFF_LIST 60688  // sList2 [8][64] i32 (2048)
#define OFF_CNT  62736  // i32[8]
#define SMEM_SZ  62768

typedef __attribute__((ext_vector_type(8))) _Float16 f16x8;
typedef __attribute__((ext_vector_type(4))) float f32x4;

#define MFMA(a, b, c) __builtin_amdgcn_mfma_f32_16x16x32_f16((a), (b), (c), 0, 0, 0)

__device__ __forceinline__ unsigned rotl32(unsigned x, int d) {
  return (x << d) | (x >> (32 - d));
}

// JAX threefry2x32, keys (0,42), counter (0, flat), partitionable fold.
__device__ __forceinline__ float gumbel_for(unsigned flat) {
  const unsigned k0 = 0u, k1 = 42u;
  const unsigned ks2 = k0 ^ k1 ^ 0x1BD11BDAu;
  unsigned x0 = 0u + k0;
  unsigned x1 = flat + k1;
#define TF_RND(r) { x0 += x1; x1 = rotl32(x1, r); x1 ^= x0; }
  TF_RND(13) TF_RND(15) TF_RND(26) TF_RND(6)
  x0 += k1;  x1 += ks2 + 1u;
  TF_RND(17) TF_RND(29) TF_RND(16) TF_RND(24)
  x0 += ks2; x1 += k0 + 2u;
  TF_RND(13) TF_RND(15) TF_RND(26) TF_RND(6)
  x0 += k0;  x1 += k1 + 3u;
  TF_RND(17) TF_RND(29) TF_RND(16) TF_RND(24)
  x0 += k1;  x1 += ks2 + 4u;
  TF_RND(13) TF_RND(15) TF_RND(26) TF_RND(6)
  x0 += ks2; x1 += k0 + 5u;
#undef TF_RND
  unsigned bits = x0 ^ x1;
  float u = __uint_as_float((bits >> 9) | 0x3f800000u) - 1.0f;
  return -logf(-logf(u + 1e-20f) + 1e-20f);
}

// ---------------------------------------------------------------------------
// prep: fp32 weights -> fragment-linear f16 (scaled split) in ws
// ---------------------------------------------------------------------------
__global__ void prep_kernel(const float* __restrict__ W_enc,
                            const float* __restrict__ W_sh,
                            const float* __restrict__ W_r1,
                            _Float16* __restrict__ ws) {
  int idx = blockIdx.x * 256 + threadIdx.x;
  if (idx < 8192) {                    // encoder: 16 tiles (nt 8 x kt 2)
    int tile = idx >> 9, r = idx & 511;
    int L = r >> 3, j = r & 7;
    int nt = tile >> 1, kt = tile & 1;
    int k = kt * 32 + (L >> 4) * 8 + j;
    int n = nt * 16 + (L & 15);
    float v = (k < 63) ? W_enc[k * 128 + n] : 0.0f;
    _Float16 h = (_Float16)v;
    ws[WS_ENC_H + idx] = h;
    ws[WS_ENC_L + idx] = (_Float16)((v - (float)h) * 2048.0f);
  } else if (idx < 8192 + 131072) {    // shape: 256 tiles (e8 x nt8 x kt4)
    int s = idx - 8192;
    int tile = s >> 9, r = s & 511;
    int L = r >> 3, j = r & 7;
    int e = tile >> 5, nt = (tile >> 2) & 7, kt = tile & 3;
    int k = kt * 32 + (L >> 4) * 8 + j;
    int n = nt * 16 + (L & 15);
    float v = W_sh[e * 16384 + k * 128 + n];
    _Float16 h = (_Float16)v;
    ws[WS_SH_H + s] = h;
    ws[WS_SH_L + s] = (_Float16)((v - (float)h) * 2048.0f);
  } else if (idx < 8192 + 131072 + 81920) {  // r1: 160 tiles (e8 x nt4 x kt5)
    int s = idx - (8192 + 131072);
    int tile = s >> 9, r = s & 511;
    int L = r >> 3, j = r & 7;
    int e = tile / 20, rr = tile % 20;
    int nt = rr / 5, kt = rr % 5;
    int k = kt * 32 + (L >> 4) * 8 + j;
    int n = nt * 16 + (L & 15);
    float v = (k < 155) ? W_r1[e * 9920 + k * 64 + n] : 0.0f;
    ws[WS_R1_H + s] = (_Float16)v;
  }
}

// ---------------------------------------------------------------------------
__global__ __launch_bounds__(NTH, 2)
void nerf_moe_kernel(const float* __restrict__ x,
                     const float* __restrict__ b_enc,
                     const float* __restrict__ b_sh,
                     const float* __restrict__ w_sig, const float* __restrict__ b_sig,
                     const float* __restrict__ b_r1,
                     const float* __restrict__ W_r2,  const float* __restrict__ b_r2,
                     const _Float16* __restrict__ wsw,
                     float* __restrict__ out) {
  __shared__ __align__(16) unsigned char smem[SMEM_SZ];
  _Float16* sYh = (_Float16*)(smem + OFF_Y);
  _Float16* sYl = (_Float16*)(smem + OFF_YL);
  float*    sRed = (float*)(smem + OFF_Y);
  float*    sH   = (float*)(smem + OFF_Y);
  float*    sW2  = (float*)(smem + OFF_YL);
  float*    sB2  = (float*)(smem + OFF_YL + 6144);
  _Float16* sSB  = (_Float16*)(smem + OFF_SB);
  _Float16* sPEh = (_Float16*)(smem + OFF_SB);
  _Float16* sPEl = (_Float16*)(smem + OFF_SB + 9216);
  _Float16* sVD  = (_Float16*)(smem + OFF_VD);
  float*    sBsc = (float*)(smem + OFF_SC);
  float*    sBsg = (float*)(smem + OFF_SG);
  int*      sBid = (int*)(smem + OFF_BID);
  unsigned long long* sMask = (unsigned long long*)(smem + OFF_MASK);
  int*      sList2 = (int*)(smem + OFF_LIST);
  int*      sCnt2  = (int*)(smem + OFF_CNT);

  const int t  = threadIdx.x;
  const int w  = t >> 6;        // wave id 0..3
  const int L  = t & 63;        // lane
  const int q  = L >> 4;        // quad 0..3
  const int c  = L & 15;
  const int n0 = blockIdx.x * PT;

  // ---- phase 0: positional encodings (f16 scaled split for xyz PE) ----
  for (int idx = t; idx < PT * 64; idx += NTH) {
    int p = idx >> 6, f = idx & 63;
    const float* xr = x + (size_t)(n0 + p) * 6;
    float v;
    if (f < 3)       v = xr[f];
    else if (f < 33) { int g = f - 3;  v = sinf(xr[g % 3] * (float)(1 << (g / 3))); }
    else if (f < 63) { int g = f - 33; v = cosf(xr[g % 3] * (float)(1 << (g / 3))); }
    else             v = 0.0f;   // K pad 63->64
    _Float16 h = (_Float16)v;
    sPEh[p * 72 + f] = h;
    sPEl[p * 72 + f] = (_Float16)((v - (float)h) * 2048.0f);
  }
  for (int idx = t; idx < PT * 27; idx += NTH) {
    int p = idx / 27, f = idx - p * 27;
    const float* xr = x + (size_t)(n0 + p) * 6 + 3;
    float v;
    if (f < 3)       v = xr[f];
    else if (f < 15) { int g = f - 3;  v = sinf(xr[g % 3] * (float)(1 << (g / 3))); }
    else             { int g = f - 15; v = cosf(xr[g % 3] * (float)(1 << (g / 3))); }
    sVD[p * 28 + f] = (_Float16)v;
  }
  __syncthreads();

  // ---- phase A: Y = relu(PE @ W_enc + b_enc) via MFMA ----
  {
    f16x8 beh[2][2], bel[2][2];      // [ntL][kt]
    #pragma unroll
    for (int ntL = 0; ntL < 2; ++ntL)
      #pragma unroll
      for (int kt = 0; kt < 2; ++kt) {
        int tile = (2 * w + ntL) * 2 + kt;
        beh[ntL][kt] = *(const f16x8*)(wsw + WS_ENC_H + tile * 512 + L * 8);
        bel[ntL][kt] = *(const f16x8*)(wsw + WS_ENC_L + tile * 512 + L * 8);
      }
    f16x8 pah[4][2], pal[4][2];
    #pragma unroll
    for (int mt = 0; mt < 4; ++mt)
      #pragma unroll
      for (int kt = 0; kt < 2; ++kt) {
        int off = (mt * 16 + c) * 72 + kt * 32 + q * 8;
        pah[mt][kt] = *(const f16x8*)(sPEh + off);
        pal[mt][kt] = *(const f16x8*)(sPEl + off);
      }
    f32x4 a1[4][2], a2[4][2];
    #pragma unroll
    for (int mt = 0; mt < 4; ++mt)
      #pragma unroll
      for (int ntL = 0; ntL < 2; ++ntL) { a1[mt][ntL] = (f32x4)0.0f; a2[mt][ntL] = (f32x4)0.0f; }
    #pragma unroll
    for (int kt = 0; kt < 2; ++kt)
      #pragma unroll
      for (int mt = 0; mt < 4; ++mt)
        #pragma unroll
        for (int ntL = 0; ntL < 2; ++ntL) {
          a1[mt][ntL] = MFMA(pah[mt][kt], beh[ntL][kt], a1[mt][ntL]);
          a2[mt][ntL] = MFMA(pah[mt][kt], bel[ntL][kt], a2[mt][ntL]);
          a2[mt][ntL] = MFMA(pal[mt][kt], beh[ntL][kt], a2[mt][ntL]);
        }
    float bb0 = b_enc[(2 * w) * 16 + c];
    float bb1 = b_enc[(2 * w + 1) * 16 + c];
    #pragma unroll
    for (int mt = 0; mt < 4; ++mt)
      #pragma unroll
      for (int ntL = 0; ntL < 2; ++ntL) {
        float bb = ntL ? bb1 : bb0;
        int col = (2 * w + ntL) * 16 + c;
        #pragma unroll
        for (int r = 0; r < 4; ++r) {
          float v = fmaxf(a1[mt][ntL][r] + a2[mt][ntL][r] * INV2048 + bb, 0.0f);
          int row = mt * 16 + q * 4 + r;
          _Float16 h = (_Float16)v;
          sYh[row * 136 + col] = h;
          sYl[row * 136 + col] = (_Float16)((v - (float)h) * 2048.0f);
        }
      }
  }
  __syncthreads();

  // ---- inter-phase: vd -> sSB cols 128..159 (zero-padded); hoist Y frags ----
  for (int idx = t; idx < PT * 32; idx += NTH) {
    int p = idx >> 5, cc = idx & 31;
    _Float16 v = (cc < 27) ? sVD[p * 28 + cc] : (_Float16)0.0f;
    sSB[p * 168 + 128 + cc] = v;
  }
  f16x8 Ah[4][4], Al[4][4];   // [mt][kt] — persists through phase B (128 VGPR)
  #pragma unroll
  for (int mt = 0; mt < 4; ++mt)
    #pragma unroll
    for (int kt = 0; kt < 4; ++kt) {
      int off = (mt * 16 + c) * 136 + kt * 32 + q * 8;
      Ah[mt][kt] = *(const f16x8*)(sYh + off);
      Al[mt][kt] = *(const f16x8*)(sYl + off);
    }
  float ws0 = w_sig[(2 * w) * 16 + c];
  float ws1 = w_sig[(2 * w + 1) * 16 + c];
  __syncthreads();   // sY region becomes sRed

  // ---- phase B: 8 experts, running gumbel-argmax ----
  #pragma unroll 1
  for (int e = 0; e < 8; ++e) {
    f32x4 a1[4][2], a2[4][2];
    #pragma unroll
    for (int mt = 0; mt < 4; ++mt)
      #pragma unroll
      for (int ntL = 0; ntL < 2; ++ntL) { a1[mt][ntL] = (f32x4)0.0f; a2[mt][ntL] = (f32x4)0.0f; }
    float bb0 = b_sh[e * 128 + (2 * w) * 16 + c];
    float bb1 = b_sh[e * 128 + (2 * w + 1) * 16 + c];
    #pragma unroll
    for (int kt = 0; kt < 4; ++kt) {
      int t0 = (e * 8 + 2 * w) * 4 + kt;
      int t1 = (e * 8 + 2 * w + 1) * 4 + kt;
      f16x8 bh0 = *(const f16x8*)(wsw + WS_SH_H + t0 * 512 + L * 8);
      f16x8 bl0 = *(const f16x8*)(wsw + WS_SH_L + t0 * 512 + L * 8);
      f16x8 bh1 = *(const f16x8*)(wsw + WS_SH_H + t1 * 512 + L * 8);
      f16x8 bl1 = *(const f16x8*)(wsw + WS_SH_L + t1 * 512 + L * 8);
      #pragma unroll
      for (int mt = 0; mt < 4; ++mt) {
        a1[mt][0] = MFMA(Ah[mt][kt], bh0, a1[mt][0]);
        a2[mt][0] = MFMA(Ah[mt][kt], bl0, a2[mt][0]);
        a2[mt][0] = MFMA(Al[mt][kt], bh0, a2[mt][0]);
        a1[mt][1] = MFMA(Ah[mt][kt], bh1, a1[mt][1]);
        a2[mt][1] = MFMA(Ah[mt][kt], bl1, a2[mt][1]);
        a2[mt][1] = MFMA(Al[mt][kt], bh1, a2[mt][1]);
      }
    }
    // sigma partials -> sRed[pt][w*16+c]
    #pragma unroll
    for (int mt = 0; mt < 4; ++mt)
      #pragma unroll
      for (int r = 0; r < 4; ++r) {
        float s0 = fmaxf(a1[mt][0][r] + a2[mt][0][r] * INV2048 + bb0, 0.0f);
        float s1 = fmaxf(a1[mt][1][r] + a2[mt][1][r] * INV2048 + bb1, 0.0f);
        sRed[(mt * 16 + q * 4 + r) * 68 + w * 16 + c] = s0 * ws0 + s1 * ws1;
      }
    __syncthreads();
    {  // stage 2: 4 partial sums per point
      int pt = t >> 2, seg = t & 3;
      const f32x4* rp = (const f32x4*)(sRed + pt * 68 + seg * 16);
      f32x4 v0 = rp[0], v1 = rp[1], v2 = rp[2], v3 = rp[3];
      float s = (v0.x + v0.y + v0.z + v0.w) + (v1.x + v1.y + v1.z + v1.w) +
                (v2.x + v2.y + v2.z + v2.w) + (v3.x + v3.y + v3.z + v3.w);
      sRed[pt * 68 + 64 + seg] = s;
    }
    __syncthreads();
    if (w == 0) {  // stage 3: sigma, score, argmax (wave 0 = pts 0..63)
      f32x4 pp = *(const f32x4*)(sRed + L * 68 + 64);
      float dotv = pp.x + pp.y + pp.z + pp.w + b_sig[0];
      float sig = fmaxf(dotv, 0.0f) + log1pf(expf(-fabsf(dotv)));
      float z = logf(sig + 1e-10f) / 0.166667f;
      float score = z + gumbel_for((unsigned)((n0 + L) * 8 + e));
      bool imp = (e == 0) || (score > sBsc[L]);
      if (imp) { sBsc[L] = score; sBsg[L] = sig; sBid[L] = e; }
      unsigned long long m = __ballot(imp);
      if (L == 0) *sMask = m;
    }
    __syncthreads();
    {  // conditional S copy for improving points
      unsigned long long m = *sMask;
      #pragma unroll
      for (int mt = 0; mt < 4; ++mt)
        #pragma unroll
        for (int r = 0; r < 4; ++r) {
          int pt = mt * 16 + q * 4 + r;
          if ((m >> pt) & 1ull) {
            float s0 = fmaxf(a1[mt][0][r] + a2[mt][0][r] * INV2048 + bb0, 0.0f);
            float s1 = fmaxf(a1[mt][1][r] + a2[mt][1][r] * INV2048 + bb1, 0.0f);
            sSB[pt * 168 + (2 * w) * 16 + c]     = (_Float16)s0;
            sSB[pt * 168 + (2 * w + 1) * 16 + c] = (_Float16)s1;
          }
        }
    }
  }
  __syncthreads();

  // ---- phase C: rgb for winners ----
  if (t < 8) {
    int cnt = 0;
    for (int p = 0; p < PT; ++p)
      if (sBid[p] == t) { sList2[t * 64 + cnt] = p; cnt++; }
    sCnt2[t] = cnt;
  }
  for (int i = t; i < 1536; i += NTH) sW2[i] = W_r2[i];  // stage W_r2 (sYl dead)
  if (t < 24) sB2[t] = b_r2[t];
  __syncthreads();

  #pragma unroll 1
  for (int ei = 0; ei < 2; ++ei) {
    int e = 2 * w + ei;
    int cnt = sCnt2[e];
    for (int mbase = 0; mbase < cnt; mbase += 16) {
      int pos = mbase + c;
      int row = (pos < cnt) ? sList2[e * 64 + pos] : 0;
      f16x8 ag[5];
      #pragma unroll
      for (int kt = 0; kt < 5; ++kt)
        ag[kt] = *(const f16x8*)(sSB + row * 168 + kt * 32 + q * 8);
      f32x4 hacc[4];
      #pragma unroll
      for (int nt = 0; nt < 4; ++nt) hacc[nt] = (f32x4)0.0f;
      #pragma unroll
      for (int nt = 0; nt < 4; ++nt)
        #pragma unroll
        for (int kt = 0; kt < 5; ++kt) {
          f16x8 bf = *(const f16x8*)(wsw + WS_R1_H + ((e * 4 + nt) * 5 + kt) * 512 + L * 8);
          hacc[nt] = MFMA(ag[kt], bf, hacc[nt]);
        }
      #pragma unroll
      for (int nt = 0; nt < 4; ++nt) {
        float bb = b_r1[e * 64 + nt * 16 + c];
        #pragma unroll
        for (int r = 0; r < 4; ++r) {
          int pos2 = mbase + q * 4 + r;
          if (pos2 < cnt) {
            int pt = sList2[e * 64 + pos2];
            sH[pt * 68 + nt * 16 + c] = fmaxf(hacc[nt][r] + bb, 0.0f);
          }
        }
      }
    }
  }
  __syncthreads();
  if (t < 192) {  // layer 2: rgb
    int pt = t / 3, o = t - pt * 3;
    int e = sBid[pt];
    const float* w2 = sW2 + e * 192 + o;
    float a = sB2[e * 3 + o];
    #pragma unroll 8
    for (int jj = 0; jj < 64; ++jj)
      a = fmaf(sH[pt * 68 + jj], w2[jj * 3], a);
    out[(size_t)(n0 + pt) * 4 + o] = 1.0f / (1.0f + expf(-a));
  }
  if (t < PT) out[(size_t)(n0 + t) * 4 + 3] = sBsg[t];
}

extern "C" void kernel_launch(void* const* d_in, const int* in_sizes, int n_in,
                              void* d_out, int out_size, void* d_ws, size_t ws_size,
                              hipStream_t stream) {
  (void)in_sizes; (void)n_in; (void)ws_size; (void)out_size;
  const float* x     = (const float*)d_in[0];
  const float* W_enc = (const float*)d_in[1];
  const float* b_enc = (const float*)d_in[2];
  const float* W_sh  = (const float*)d_in[3];
  const float* b_sh  = (const float*)d_in[4];
  const float* w_sig = (const float*)d_in[5];
  const float* b_sig = (const float*)d_in[6];
  const float* W_r1  = (const float*)d_in[7];
  const float* b_r1  = (const float*)d_in[8];
  const float* W_r2  = (const float*)d_in[9];
  const float* b_r2  = (const float*)d_in[10];
  _Float16* ws = (_Float16*)d_ws;     // needs 720896 B
  float* outp = (float*)d_out;
  prep_kernel<<<864, 256, 0, stream>>>(W_enc, W_sh, W_r1, ws);
  nerf_moe_kernel<<<NBLK, NTH, 0, stream>>>(x, b_enc, b_sh, w_sig, b_sig,
                                            b_r1, W_r2, b_r2, ws, outp);
}

// Round 3
// 286.998 us; speedup vs baseline: 3.6268x; 1.1222x over previous
//
#include <hip/hip_runtime.h>
#include <hip/hip_bf16.h>

// ---------------------------------------------------------------------------
// GumbelNeRF fused kernel, round 3: barrier-free expert loop.
//
// vs round 2 (322us, MfmaUtil 17%, 24 barriers in expert loop):
//  - Pass 1 (8 experts) keeps S only transiently in regs; sigma partials are
//    reduced IN-REGISTER via DPP row_ror adds (VALU pipe) + cndmask select,
//    accumulated into 8 VGPRs, written to LDS once after the loop. Zero
//    barriers / zero LDS ops inside the expert loop.
//  - Gumbels precomputed by all threads in phase 0 (data-independent).
//  - Argmax in one pass (t<64); winner's S recomputed in pass 2a (f16
//    hi-only, ok for rgb tolerance) bucketed by expert, fused with rgb MLP.
//  - ~9 barriers total vs ~27.
// Sigma/score path keeps the f16 3-product split (hi + lo/2048) end-to-end
// fp32 accumulate — identical numerics to the passing round-2 kernel.
// ---------------------------------------------------------------------------

#define NPTS 131072
#define PT 64
#define NTH 256
#define NBLK (NPTS / PT)
#define INV2048 (1.0f / 2048.0f)

// ws sections (f16 element offsets) — prep layout identical to round 2
#define WS_ENC_H 0
#define WS_ENC_L 8192
#define WS_SH_H  16384
#define WS_SH_L  147456
#define WS_R1_H  278528

// LDS byte offsets, total 54336
#define OFF_YH   0      // sYh [64][136] f16 = 17408 ; pass2b+: sH [64][68] f32
#define OFF_B    17408  // sPEh[64][72](9216) + sPEl @+9216 | sYl [64][136] | sSB [64][168] f16 (21504)
#define OFF_VD   38912  // sVD [64][28] f16 = 3584
#define OFF_RED  42496  // sRed [64][36] f32 = 9216 (stride 36: b128-aligned, bank-spread)
#define OFF_GUM  51712  // sGum [512] f32 = 2048
#define OFF_BID  53760  // i32[64]
#define OFF_LIST 54016  // i32[64] slot->pt
#define OFF_CNT  54272  // i32[8]
#define OFF_OFFS 54304  // i32[8]
#define SMEM_SZ  54336

typedef __attribute__((ext_vector_type(8))) _Float16 f16x8;
typedef __attribute__((ext_vector_type(4))) float f32x4;

#define MFMA(a, b, c) __builtin_amdgcn_mfma_f32_16x16x32_f16((a), (b), (c), 0, 0, 0)

__device__ __forceinline__ unsigned rotl32(unsigned x, int d) {
  return (x << d) | (x >> (32 - d));
}

// JAX threefry2x32, keys (0,42), counter (0, flat), partitionable fold.
__device__ __forceinline__ float gumbel_for(unsigned flat) {
  const unsigned k0 = 0u, k1 = 42u;
  const unsigned ks2 = k0 ^ k1 ^ 0x1BD11BDAu;
  unsigned x0 = 0u + k0;
  unsigned x1 = flat + k1;
#define TF_RND(r) { x0 += x1; x1 = rotl32(x1, r); x1 ^= x0; }
  TF_RND(13) TF_RND(15) TF_RND(26) TF_RND(6)
  x0 += k1;  x1 += ks2 + 1u;
  TF_RND(17) TF_RND(29) TF_RND(16) TF_RND(24)
  x0 += ks2; x1 += k0 + 2u;
  TF_RND(13) TF_RND(15) TF_RND(26) TF_RND(6)
  x0 += k0;  x1 += k1 + 3u;
  TF_RND(17) TF_RND(29) TF_RND(16) TF_RND(24)
  x0 += k1;  x1 += ks2 + 4u;
  TF_RND(13) TF_RND(15) TF_RND(26) TF_RND(6)
  x0 += ks2; x1 += k0 + 5u;
#undef TF_RND
  unsigned bits = x0 ^ x1;
  float u = __uint_as_float((bits >> 9) | 0x3f800000u) - 1.0f;
  return -logf(-logf(u + 1e-20f) + 1e-20f);
}

// sum over the 16 lanes of a DPP row (c-dimension) via rotate-adds; VALU only
__device__ __forceinline__ float dpp_rowsum16(float v) {
  int x;
  x = __builtin_amdgcn_update_dpp(0, __builtin_bit_cast(int, v), 0x128, 0xf, 0xf, true);
  v += __builtin_bit_cast(float, x);   // + ror8
  x = __builtin_amdgcn_update_dpp(0, __builtin_bit_cast(int, v), 0x124, 0xf, 0xf, true);
  v += __builtin_bit_cast(float, x);   // + ror4
  x = __builtin_amdgcn_update_dpp(0, __builtin_bit_cast(int, v), 0x122, 0xf, 0xf, true);
  v += __builtin_bit_cast(float, x);   // + ror2
  x = __builtin_amdgcn_update_dpp(0, __builtin_bit_cast(int, v), 0x121, 0xf, 0xf, true);
  v += __builtin_bit_cast(float, x);   // + ror1
  return v;
}

// ---------------------------------------------------------------------------
// prep: fp32 weights -> fragment-linear f16 (scaled split) in ws  [round 2]
// ---------------------------------------------------------------------------
__global__ void prep_kernel(const float* __restrict__ W_enc,
                            const float* __restrict__ W_sh,
                            const float* __restrict__ W_r1,
                            _Float16* __restrict__ ws) {
  int idx = blockIdx.x * 256 + threadIdx.x;
  if (idx < 8192) {
    int tile = idx >> 9, r = idx & 511;
    int L = r >> 3, j = r & 7;
    int nt = tile >> 1, kt = tile & 1;
    int k = kt * 32 + (L >> 4) * 8 + j;
    int n = nt * 16 + (L & 15);
    float v = (k < 63) ? W_enc[k * 128 + n] : 0.0f;
    _Float16 h = (_Float16)v;
    ws[WS_ENC_H + idx] = h;
    ws[WS_ENC_L + idx] = (_Float16)((v - (float)h) * 2048.0f);
  } else if (idx < 8192 + 131072) {
    int s = idx - 8192;
    int tile = s >> 9, r = s & 511;
    int L = r >> 3, j = r & 7;
    int e = tile >> 5, nt = (tile >> 2) & 7, kt = tile & 3;
    int k = kt * 32 + (L >> 4) * 8 + j;
    int n = nt * 16 + (L & 15);
    float v = W_sh[e * 16384 + k * 128 + n];
    _Float16 h = (_Float16)v;
    ws[WS_SH_H + s] = h;
    ws[WS_SH_L + s] = (_Float16)((v - (float)h) * 2048.0f);
  } else if (idx < 8192 + 131072 + 81920) {
    int s = idx - (8192 + 131072);
    int tile = s >> 9, r = s & 511;
    int L = r >> 3, j = r & 7;
    int e = tile / 20, rr = tile % 20;
    int nt = rr / 5, kt = rr % 5;
    int k = kt * 32 + (L >> 4) * 8 + j;
    int n = nt * 16 + (L & 15);
    float v = (k < 155) ? W_r1[e * 9920 + k * 64 + n] : 0.0f;
    ws[WS_R1_H + s] = (_Float16)v;
  }
}

// ---------------------------------------------------------------------------
__global__ __launch_bounds__(NTH, 2)
void nerf_moe_kernel(const float* __restrict__ x,
                     const float* __restrict__ b_enc,
                     const float* __restrict__ b_sh,
                     const float* __restrict__ w_sig, const float* __restrict__ b_sig,
                     const float* __restrict__ b_r1,
                     const float* __restrict__ W_r2,  const float* __restrict__ b_r2,
                     const _Float16* __restrict__ wsw,
                     float* __restrict__ out) {
  __shared__ __align__(16) unsigned char smem[SMEM_SZ];
  _Float16* sYh  = (_Float16*)(smem + OFF_YH);
  float*    sH   = (float*)(smem + OFF_YH);
  _Float16* sYl  = (_Float16*)(smem + OFF_B);
  _Float16* sPEh = (_Float16*)(smem + OFF_B);
  _Float16* sPEl = (_Float16*)(smem + OFF_B + 9216);
  _Float16* sSB  = (_Float16*)(smem + OFF_B);
  _Float16* sVD  = (_Float16*)(smem + OFF_VD);
  float*    sRed = (float*)(smem + OFF_RED);
  float*    sGum = (float*)(smem + OFF_GUM);
  int*      sBid = (int*)(smem + OFF_BID);
  int*      sList = (int*)(smem + OFF_LIST);
  int*      sCnt = (int*)(smem + OFF_CNT);
  int*      sOff = (int*)(smem + OFF_OFFS);

  const int t  = threadIdx.x;
  const int w  = t >> 6;        // wave id 0..3
  const int L  = t & 63;        // lane
  const int q  = L >> 4;        // quad 0..3
  const int c  = L & 15;
  const int n0 = blockIdx.x * PT;

  // ---- phase 0: positional encodings + gumbel precompute ----
  for (int idx = t; idx < PT * 64; idx += NTH) {
    int p = idx >> 6, f = idx & 63;
    const float* xr = x + (size_t)(n0 + p) * 6;
    float v;
    if (f < 3)       v = xr[f];
    else if (f < 33) { int g = f - 3;  v = sinf(xr[g % 3] * (float)(1 << (g / 3))); }
    else if (f < 63) { int g = f - 33; v = cosf(xr[g % 3] * (float)(1 << (g / 3))); }
    else             v = 0.0f;
    _Float16 h = (_Float16)v;
    sPEh[p * 72 + f] = h;
    sPEl[p * 72 + f] = (_Float16)((v - (float)h) * 2048.0f);
  }
  for (int idx = t; idx < PT * 27; idx += NTH) {
    int p = idx / 27, f = idx - p * 27;
    const float* xr = x + (size_t)(n0 + p) * 6 + 3;
    float v;
    if (f < 3)       v = xr[f];
    else if (f < 15) { int g = f - 3;  v = sinf(xr[g % 3] * (float)(1 << (g / 3))); }
    else             { int g = f - 15; v = cosf(xr[g % 3] * (float)(1 << (g / 3))); }
    sVD[p * 28 + f] = (_Float16)v;
  }
  sGum[t]       = gumbel_for((unsigned)(n0 * 8 + t));
  sGum[t + 256] = gumbel_for((unsigned)(n0 * 8 + t + 256));
  __syncthreads();                                   // (1)

  // ---- phase A: Y = relu(PE @ W_enc + b) via MFMA, N-split ----
  {
    f16x8 beh[2][2], bel[2][2];
    #pragma unroll
    for (int ntL = 0; ntL < 2; ++ntL)
      #pragma unroll
      for (int kt = 0; kt < 2; ++kt) {
        int tile = (2 * w + ntL) * 2 + kt;
        beh[ntL][kt] = *(const f16x8*)(wsw + WS_ENC_H + tile * 512 + L * 8);
        bel[ntL][kt] = *(const f16x8*)(wsw + WS_ENC_L + tile * 512 + L * 8);
      }
    f16x8 pah[4][2], pal[4][2];
    #pragma unroll
    for (int mt = 0; mt < 4; ++mt)
      #pragma unroll
      for (int kt = 0; kt < 2; ++kt) {
        int off = (mt * 16 + c) * 72 + kt * 32 + q * 8;
        pah[mt][kt] = *(const f16x8*)(sPEh + off);
        pal[mt][kt] = *(const f16x8*)(sPEl + off);
      }
    f32x4 a1[4][2], a2[4][2];
    #pragma unroll
    for (int mt = 0; mt < 4; ++mt)
      #pragma unroll
      for (int ntL = 0; ntL < 2; ++ntL) { a1[mt][ntL] = (f32x4)0.0f; a2[mt][ntL] = (f32x4)0.0f; }
    #pragma unroll
    for (int kt = 0; kt < 2; ++kt)
      #pragma unroll
      for (int mt = 0; mt < 4; ++mt)
        #pragma unroll
        for (int ntL = 0; ntL < 2; ++ntL) {
          a1[mt][ntL] = MFMA(pah[mt][kt], beh[ntL][kt], a1[mt][ntL]);
          a2[mt][ntL] = MFMA(pah[mt][kt], bel[ntL][kt], a2[mt][ntL]);
          a2[mt][ntL] = MFMA(pal[mt][kt], beh[ntL][kt], a2[mt][ntL]);
        }
    __syncthreads();                                 // (2) sPE reads done -> sYl writable
    float bb0 = b_enc[(2 * w) * 16 + c];
    float bb1 = b_enc[(2 * w + 1) * 16 + c];
    #pragma unroll
    for (int mt = 0; mt < 4; ++mt)
      #pragma unroll
      for (int ntL = 0; ntL < 2; ++ntL) {
        float bb = ntL ? bb1 : bb0;
        int col = (2 * w + ntL) * 16 + c;
        #pragma unroll
        for (int r = 0; r < 4; ++r) {
          float v = fmaxf(a1[mt][ntL][r] + a2[mt][ntL][r] * INV2048 + bb, 0.0f);
          int row = mt * 16 + q * 4 + r;
          _Float16 h = (_Float16)v;
          sYh[row * 136 + col] = h;
          sYl[row * 136 + col] = (_Float16)((v - (float)h) * 2048.0f);
        }
      }
  }
  __syncthreads();                                   // (3)

  // hoist Y A-frags (hi+lo, 128 VGPR) — persists through pass 1
  f16x8 Ah[4][4], Al[4][4];
  #pragma unroll
  for (int mt = 0; mt < 4; ++mt)
    #pragma unroll
    for (int kt = 0; kt < 4; ++kt) {
      int off = (mt * 16 + c) * 136 + kt * 32 + q * 8;
      Ah[mt][kt] = *(const f16x8*)(sYh + off);
      Al[mt][kt] = *(const f16x8*)(sYl + off);
    }
  const float ws0 = w_sig[(2 * w) * 16 + c];
  const float ws1 = w_sig[(2 * w + 1) * 16 + c];
  const bool b3 = (c & 8) != 0, b2g = (c & 4) != 0, b1 = (c & 2) != 0, b0 = (c & 1) != 0;

  // ---- pass 1: 8 experts, ZERO barriers; sigma partials in regs ----
  float sigAcc[8];
  #pragma unroll 1
  for (int e = 0; e < 8; ++e) {
    float sp[16];
    #pragma unroll
    for (int i = 0; i < 16; ++i) sp[i] = 0.0f;
    #pragma unroll
    for (int ntL = 0; ntL < 2; ++ntL) {
      f32x4 a1[4], a2[4];
      #pragma unroll
      for (int mt = 0; mt < 4; ++mt) { a1[mt] = (f32x4)0.0f; a2[mt] = (f32x4)0.0f; }
      #pragma unroll
      for (int kt = 0; kt < 4; ++kt) {
        int tile = (e * 8 + 2 * w + ntL) * 4 + kt;
        f16x8 bh = *(const f16x8*)(wsw + WS_SH_H + tile * 512 + L * 8);
        f16x8 bl = *(const f16x8*)(wsw + WS_SH_L + tile * 512 + L * 8);
        #pragma unroll
        for (int mt = 0; mt < 4; ++mt) {
          a1[mt] = MFMA(Ah[mt][kt], bh, a1[mt]);
          a2[mt] = MFMA(Ah[mt][kt], bl, a2[mt]);
          a2[mt] = MFMA(Al[mt][kt], bh, a2[mt]);
        }
      }
      float wsC = ntL ? ws1 : ws0;
      float bb = b_sh[e * 128 + (2 * w + ntL) * 16 + c];
      #pragma unroll
      for (int mt = 0; mt < 4; ++mt)
        #pragma unroll
        for (int r = 0; r < 4; ++r) {
          float s = fmaxf(a1[mt][r] + a2[mt][r] * INV2048 + bb, 0.0f);
          sp[mt * 4 + r] = fmaf(s, wsC, sp[mt * 4 + r]);
        }
    }
    // reduce over c-lanes (DPP, VALU pipe), then select this lane's row
    #pragma unroll
    for (int i = 0; i < 16; ++i) sp[i] = dpp_rowsum16(sp[i]);
    float u0 = b2g ? sp[4]  : sp[0],  u1 = b2g ? sp[5]  : sp[1];
    float u2 = b2g ? sp[6]  : sp[2],  u3 = b2g ? sp[7]  : sp[3];
    float v0 = b2g ? sp[12] : sp[8],  v1 = b2g ? sp[13] : sp[9];
    float v2 = b2g ? sp[14] : sp[10], v3 = b2g ? sp[15] : sp[11];
    float r0 = b3 ? v0 : u0, r1 = b3 ? v1 : u1, r2 = b3 ? v2 : u2, r3 = b3 ? v3 : u3;
    float rr = b1 ? (b0 ? r3 : r2) : (b0 ? r1 : r0);
    sigAcc[e] = rr;   // partial (this wave's 32 cols) for row (c>>2)*16+q*4+(c&3)
  }
  {
    int R = (c >> 2) * 16 + q * 4 + (c & 3);
    f32x4 g0 = { sigAcc[0], sigAcc[1], sigAcc[2], sigAcc[3] };
    f32x4 g1 = { sigAcc[4], sigAcc[5], sigAcc[6], sigAcc[7] };
    *(f32x4*)(sRed + R * 36 + w * 8)     = g0;
    *(f32x4*)(sRed + R * 36 + w * 8 + 4) = g1;
  }
  __syncthreads();                                   // (4)

  // ---- argmax: one pass, t<64 ----
  if (t < PT) {
    float best = 0.0f, bsig = 0.0f;
    int bide = 0;
    const float bs = b_sig[0];
    #pragma unroll
    for (int e = 0; e < 8; ++e) {
      float s = sRed[t * 36 + e] + sRed[t * 36 + 8 + e] +
                sRed[t * 36 + 16 + e] + sRed[t * 36 + 24 + e];
      float dotv = s + bs;
      float sig = fmaxf(dotv, 0.0f) + log1pf(expf(-fabsf(dotv)));
      float z = logf(sig + 1e-10f) / 0.166667f;
      float score = z + sGum[t * 8 + e];
      if (e == 0 || score > best) { best = score; bsig = sig; bide = e; }
    }
    sBid[t] = bide;
    out[(size_t)(n0 + t) * 4 + 3] = bsig;
  }
  __syncthreads();                                   // (5)

  // ---- bucket lists (concatenated slots) ----
  if (t < 8) {
    int cnt = 0;
    for (int p = 0; p < PT; ++p) cnt += (sBid[p] == t);
    sCnt[t] = cnt;
  }
  __syncthreads();                                   // (6)
  if (t < 8) {
    int off = 0;
    for (int i = 0; i < t; ++i) off += sCnt[i];
    sOff[t] = off;
    int k = off;
    for (int p = 0; p < PT; ++p) if (sBid[p] == t) sList[k++] = p;
  }
  __syncthreads();                                   // (7)

  // ---- pass 2a: recompute winner S (f16 hi-only) bucketed; fill vd cols ----
  for (int idx = t; idx < PT * 32; idx += NTH) {
    int s = idx >> 5, cc = idx & 31;
    _Float16 v = (cc < 27) ? sVD[sList[s] * 28 + cc] : (_Float16)0.0f;
    sSB[s * 168 + 128 + cc] = v;
  }
  #pragma unroll 1
  for (int ei = 0; ei < 2; ++ei) {
    int e = 2 * w + ei;
    int cnt = sCnt[e], off = sOff[e];
    for (int base = 0; base < cnt; base += 16) {
      int sidx = base + c; if (sidx >= cnt) sidx = cnt - 1;
      int pt = sList[off + sidx];
      f16x8 ah[4];
      #pragma unroll
      for (int kt = 0; kt < 4; ++kt)
        ah[kt] = *(const f16x8*)(sYh + pt * 136 + kt * 32 + q * 8);
      f32x4 acc[8];
      #pragma unroll
      for (int nt = 0; nt < 8; ++nt) acc[nt] = (f32x4)0.0f;
      #pragma unroll
      for (int nt = 0; nt < 8; ++nt)
        #pragma unroll
        for (int kt = 0; kt < 4; ++kt) {
          f16x8 b = *(const f16x8*)(wsw + WS_SH_H + ((e * 8 + nt) * 4 + kt) * 512 + L * 8);
          acc[nt] = MFMA(ah[kt], b, acc[nt]);
        }
      #pragma unroll
      for (int nt = 0; nt < 8; ++nt) {
        float bb = b_sh[e * 128 + nt * 16 + c];
        #pragma unroll
        for (int r = 0; r < 4; ++r) {
          int m = q * 4 + r;
          if (base + m < cnt)
            sSB[(off + base + m) * 168 + nt * 16 + c] =
                (_Float16)fmaxf(acc[nt][r] + bb, 0.0f);
        }
      }
    }
  }
  __syncthreads();                                   // (8) sYh dead -> sH writable

  // ---- pass 2b: rgb layer 1 via MFMA ([S;vd] @ W_r1) ----
  #pragma unroll 1
  for (int ei = 0; ei < 2; ++ei) {
    int e = 2 * w + ei;
    int cnt = sCnt[e], off = sOff[e];
    for (int base = 0; base < cnt; base += 16) {
      int sidx = base + c; if (sidx >= cnt) sidx = cnt - 1;
      int slot = off + sidx;
      f16x8 ag[5];
      #pragma unroll
      for (int kt = 0; kt < 5; ++kt)
        ag[kt] = *(const f16x8*)(sSB + slot * 168 + kt * 32 + q * 8);
      f32x4 hacc[4];
      #pragma unroll
      for (int nt = 0; nt < 4; ++nt) hacc[nt] = (f32x4)0.0f;
      #pragma unroll
      for (int nt = 0; nt < 4; ++nt)
        #pragma unroll
        for (int kt = 0; kt < 5; ++kt) {
          f16x8 bf = *(const f16x8*)(wsw + WS_R1_H + ((e * 4 + nt) * 5 + kt) * 512 + L * 8);
          hacc[nt] = MFMA(ag[kt], bf, hacc[nt]);
        }
      #pragma unroll
      for (int nt = 0; nt < 4; ++nt) {
        float bb = b_r1[e * 64 + nt * 16 + c];
        #pragma unroll
        for (int r = 0; r < 4; ++r) {
          int m = q * 4 + r;
          if (base + m < cnt)
            sH[(off + base + m) * 68 + nt * 16 + c] = fmaxf(hacc[nt][r] + bb, 0.0f);
        }
      }
    }
  }
  __syncthreads();                                   // (9)

  // ---- layer 2: rgb = sigmoid(h @ W_r2 + b) ----
  if (t < 192) {
    int s = t / 3, o = t - s * 3;
    int pt = sList[s];
    int e = sBid[pt];
    float a = b_r2[e * 3 + o];
    const float* w2 = W_r2 + e * 192 + o;
    #pragma unroll 8
    for (int j = 0; j < 64; ++j)
      a = fmaf(sH[s * 68 + j], w2[j * 3], a);
    out[(size_t)(n0 + pt) * 4 + o] = 1.0f / (1.0f + expf(-a));
  }
}

extern "C" void kernel_launch(void* const* d_in, const int* in_sizes, int n_in,
                              void* d_out, int out_size, void* d_ws, size_t ws_size,
                              hipStream_t stream) {
  (void)in_sizes; (void)n_in; (void)ws_size; (void)out_size;
  const float* x     = (const float*)d_in[0];
  const float* W_enc = (const float*)d_in[1];
  const float* b_enc = (const float*)d_in[2];
  const float* W_sh  = (const float*)d_in[3];
  const float* b_sh  = (const float*)d_in[4];
  const float* w_sig = (const float*)d_in[5];
  const float* b_sig = (const float*)d_in[6];
  const float* W_r1  = (const float*)d_in[7];
  const float* b_r1  = (const float*)d_in[8];
  const float* W_r2  = (const float*)d_in[9];
  const float* b_r2  = (const float*)d_in[10];
  _Float16* ws = (_Float16*)d_ws;     // needs 720896 B
  float* outp = (float*)d_out;
  prep_kernel<<<864, 256, 0, stream>>>(W_enc, W_sh, W_r1, ws);
  nerf_moe_kernel<<<NBLK, NTH, 0, stream>>>(x, b_enc, b_sh, w_sig, b_sig,
                                            b_r1, W_r2, b_r2, ws, outp);
}